// Round 14
// baseline (173.283 us; speedup 1.0000x reference)
//
#include <hip/hip_runtime.h>

#define NTAG 32
#define START 30
#define STOP 31
#define LOG2E 1.44269504088896340736f
#define LN2 0.69314718055994530942f

__device__ __forceinline__ float fexp2(float x) {
#if __has_builtin(__builtin_amdgcn_exp2f)
    return __builtin_amdgcn_exp2f(x);   // v_exp_f32: 2^x
#else
    return exp2f(x);
#endif
}
__device__ __forceinline__ float flog2(float x) {
#if __has_builtin(__builtin_amdgcn_logf)
    return __builtin_amdgcn_logf(x);    // v_log_f32: log2(x)
#else
    return log2f(x);
#endif
}

// Half-exchange (v_permlane32_swap_b32, VALU).  a==b==x on entry ->
// {a,b} = {own, partner} in SOME order -> a+b direction-proof.  R8-proven.
__device__ __forceinline__ void plswap(float &a, float &b) {
#if __has_builtin(__builtin_amdgcn_permlane32_swap)
    auto r = __builtin_amdgcn_permlane32_swap(__float_as_int(a), __float_as_int(b),
                                              false, false);
    a = __int_as_float(r[0]);
    b = __int_as_float(r[1]);
#else
    asm volatile("v_permlane32_swap_b32 %0, %1" : "+v"(a), "+v"(b));
#endif
}

#define REPEAT16(M) \
    M(0) M(1) M(2) M(3) M(4) M(5) M(6) M(7) \
    M(8) M(9) M(10) M(11) M(12) M(13) M(14) M(15)

// One LINEAR-domain step, split-dot (R8/R12 layout: lanes j and j+32 both
// own output j; lane j handles input terms 0..15, lane j+32 terms 16..31).
// Broadcast via 16x ds_bpermute_b32: a register crossbar through the DS
// pipe - no LDS memory write, no store->load RAW (the R12 chain's ~240cy
// term).  Source lanes ib..ib+15 (lanes 0-31 hold exact state replicas);
// addresses are loop-invariant.  All 16 pulls depend only on y_ and
// pipeline back-to-back; the scalar FMA tree (i-ascending, acc = i&3,
// R0-proven grouping) chases the returns.  Cross-half combine via
// permlane32_swap.  PRE=0 fwd: S <- (M^T S)*F;  PRE=1 bwd: S <- M(S*F).
// RN: WAVE-UNIFORM exact pow2 renorm via readfirstlane (R0-proven; the
// bpermute g0 differs per half so Q0-style k would be the R7 bug).
#define BPERM_DECL(k) const int g##k = \
    __builtin_amdgcn_ds_bpermute(bpa + 4 * (k), yi_);
#define FMA_T(k) { const float sf_ = __int_as_float(g##k); \
    if      (((k) & 3) == 0) a0_ = (k) ? fmaf(sf_, E_##k, a0_) : (sf_ * E_0); \
    else if (((k) & 3) == 1) a1_ = ((k) == 1) ? (sf_ * E_1) : fmaf(sf_, E_##k, a1_); \
    else if (((k) & 3) == 2) a2_ = ((k) == 2) ? (sf_ * E_2) : fmaf(sf_, E_##k, a2_); \
    else                     a3_ = ((k) == 3) ? (sf_ * E_3) : fmaf(sf_, E_##k, a3_); }

#define STEP_CORE(fraw_, PRE, RN) { \
    const float F_ = fexp2((fraw_) * LOG2E); \
    const float y_ = (PRE) ? (S * F_) : S; \
    const int yi_ = __float_as_int(y_); \
    REPEAT16(BPERM_DECL) \
    float a0_, a1_, a2_, a3_; \
    REPEAT16(FMA_T) \
    const float part_ = (a0_ + a1_) + (a2_ + a3_); \
    float px_ = part_, py_ = part_; \
    plswap(px_, py_); \
    const float r_ = px_ + py_; \
    S = (PRE) ? r_ : (r_ * F_); \
    if (RN) { \
        const int b0_ = __builtin_amdgcn_readfirstlane(__float_as_int(S)); \
        const int k_ = ((b0_ >> 23) & 0xff) - 127; \
        S = __int_as_float(__float_as_int(S) - (k_ << 23)); \
        M2i += k_; } }

// main-loop reload: rolling per-lane byte offset (R12-proven; bounds:
// fwd reload times 17..h+15 <= 271 < L; bwd reload times n-17..h-16 >= 0
// whenever the main loop runs).
#define STEP_RELOAD(FS, PRE, RN) { const float fraw_ = FS; \
    { FS = *(const float*)((const char*)frow + voff); voff += dStep; } \
    STEP_CORE(fraw_, PRE, RN) }

#define STEP_NR(FS, PRE, RN) { const float fraw_ = FS; STEP_CORE(fraw_, PRE, RN) }

// zero-instruction insurance against E remat/spill
#define PIN_E \
    asm volatile("" : "+v"(E_0),  "+v"(E_1),  "+v"(E_2),  "+v"(E_3), \
                      "+v"(E_4),  "+v"(E_5),  "+v"(E_6),  "+v"(E_7)); \
    asm volatile("" : "+v"(E_8),  "+v"(E_9),  "+v"(E_10), "+v"(E_11), \
                      "+v"(E_12), "+v"(E_13), "+v"(E_14), "+v"(E_15));

// Block = 768 threads = 12 waves, grid = B/4 = 256 blocks = 1 block/CU.
// Waves 0-3: FORWARD half-chains (batch blk*4+w, split-dot, 64 lanes).
// Waves 4-7: BACKWARD half-chains.  Waves 8-11: gold gathers.
// SIMD s hosts fwd(b_s) + bwd(b_s) + gold; chain waves overlap to max
// (R11), so wall = solo per-step latency x 256 - this round attacks the
// solo latency's DS term.
__global__ __launch_bounds__(768, 1) void crf_nll_kernel(
    const float* __restrict__ feats,   // B x L x 32
    const float* __restrict__ trans,   // 32 x 32
    const int*   __restrict__ tags,    // B x L
    const int*   __restrict__ wsl,     // B
    float* __restrict__ out, int B, int L)
{
    __shared__ float strans[NTAG * NTAG];
    __shared__ float sRes[8][NTAG];    // fwd S (0-3), bwd x (4-7)
    __shared__ int   sM2[8];           // per-wave renorm exponent (uniform)
    for (int i = threadIdx.x; i < NTAG * NTAG; i += 768) strans[i] = trans[i];
    __syncthreads();

    const int wave = threadIdx.x >> 6;
    const int lane = threadIdx.x & 63;

    if (wave < 8) {
        const int dir = wave >> 2;            // 0 = fwd, 1 = bwd
        int b = blockIdx.x * 4 + (wave & 3);
        if (b >= B) b = B - 1;
        b = __builtin_amdgcn_readfirstlane(b);
        const int j = lane & 31;
        const bool up = lane >= 32;
        const int ib = up ? 16 : 0;           // this half's input-term base
        const int bpa = ib * 4;               // bpermute base byte addr (src lane*4)
        const int n = __builtin_amdgcn_readfirstlane(wsl[b]);
        const int h = (n + 1) >> 1;           // meet point
        const float* __restrict__ frow = feats + (size_t)b * L * NTAG;

        float S;
        int M2i = 0;

        if (dir == 0) {
            // ========== forward: S(0) -> S(h-1), cnt = h-1 steps ============
            // E_k = e^trans[ib+k][j] (column j of M)
#define DECL_E(k) float E_##k = fexp2(strans[(ib + (k)) * NTAG + j] * LOG2E);
            REPEAT16(DECL_E)
#undef DECL_E
            S = fexp2((strans[START * NTAG + j] + frow[j]) * LOG2E);
            int voff = (17 * NTAG + j) * 4;   // first reload = time 17
            const int dStep = NTAG * 4;
#define LDF(t_) frow[(((t_) < L - 1) ? (t_) : (L - 1)) * NTAG + j]
            float fA0 = LDF(1),  fA1 = LDF(2),  fA2 = LDF(3),  fA3 = LDF(4),
                  fA4 = LDF(5),  fA5 = LDF(6),  fA6 = LDF(7),  fA7 = LDF(8);
            float fB0 = LDF(9),  fB1 = LDF(10), fB2 = LDF(11), fB3 = LDF(12),
                  fB4 = LDF(13), fB5 = LDF(14), fB6 = LDF(15), fB7 = LDF(16);
#undef LDF
            int t = 1;
            for (; t + 16 <= h; t += 16) {
                PIN_E
                STEP_RELOAD(fA0, 0, 0)
                STEP_RELOAD(fA1, 0, 0)
                STEP_RELOAD(fA2, 0, 0)
                STEP_RELOAD(fA3, 0, 0)
                STEP_RELOAD(fA4, 0, 0)
                STEP_RELOAD(fA5, 0, 0)
                STEP_RELOAD(fA6, 0, 0)
                STEP_RELOAD(fA7, 0, 1)        // exact pow2 renorm /8
                STEP_RELOAD(fB0, 0, 0)
                STEP_RELOAD(fB1, 0, 0)
                STEP_RELOAD(fB2, 0, 0)
                STEP_RELOAD(fB3, 0, 0)
                STEP_RELOAD(fB4, 0, 0)
                STEP_RELOAD(fB5, 0, 0)
                STEP_RELOAD(fB6, 0, 0)
                STEP_RELOAD(fB7, 0, 1)
            }
            if (t + 0  < h) { STEP_NR(fA0, 0, 1) }
            if (t + 1  < h) { STEP_NR(fA1, 0, 1) }
            if (t + 2  < h) { STEP_NR(fA2, 0, 1) }
            if (t + 3  < h) { STEP_NR(fA3, 0, 1) }
            if (t + 4  < h) { STEP_NR(fA4, 0, 1) }
            if (t + 5  < h) { STEP_NR(fA5, 0, 1) }
            if (t + 6  < h) { STEP_NR(fA6, 0, 1) }
            if (t + 7  < h) { STEP_NR(fA7, 0, 1) }
            if (t + 8  < h) { STEP_NR(fB0, 0, 1) }
            if (t + 9  < h) { STEP_NR(fB1, 0, 1) }
            if (t + 10 < h) { STEP_NR(fB2, 0, 1) }
            if (t + 11 < h) { STEP_NR(fB3, 0, 1) }
            if (t + 12 < h) { STEP_NR(fB4, 0, 1) }
            if (t + 13 < h) { STEP_NR(fB5, 0, 1) }
            if (t + 14 < h) { STEP_NR(fB6, 0, 1) }
        } else {
            // ========== backward: x = u, t = n-1 .. h, cnt = n-h ============
            // E_k = e^trans[j][ib+k] (row j of M)
#define DECL_E(k) float E_##k = fexp2(strans[j * NTAG + ib + (k)] * LOG2E);
            REPEAT16(DECL_E)
#undef DECL_E
            S = fexp2(strans[j * NTAG + STOP] * LOG2E);   // u_j
            const int cnt = n - h;
            int voff = ((n - 17) * NTAG + j) * 4;   // first reload = time n-17
            const int dStep = -(NTAG * 4);
#define LDB(s_) frow[(((n - 1 - (s_)) > 0) ? (n - 1 - (s_)) : 0) * NTAG + j]
            float gA0 = LDB(0),  gA1 = LDB(1),  gA2 = LDB(2),  gA3 = LDB(3),
                  gA4 = LDB(4),  gA5 = LDB(5),  gA6 = LDB(6),  gA7 = LDB(7);
            float gB0 = LDB(8),  gB1 = LDB(9),  gB2 = LDB(10), gB3 = LDB(11),
                  gB4 = LDB(12), gB5 = LDB(13), gB6 = LDB(14), gB7 = LDB(15);
#undef LDB
            int s = 0;
            for (; s + 16 <= cnt; s += 16) {
                PIN_E
                STEP_RELOAD(gA0, 1, 0)
                STEP_RELOAD(gA1, 1, 0)
                STEP_RELOAD(gA2, 1, 0)
                STEP_RELOAD(gA3, 1, 0)
                STEP_RELOAD(gA4, 1, 0)
                STEP_RELOAD(gA5, 1, 0)
                STEP_RELOAD(gA6, 1, 0)
                STEP_RELOAD(gA7, 1, 1)        // exact pow2 renorm /8
                STEP_RELOAD(gB0, 1, 0)
                STEP_RELOAD(gB1, 1, 0)
                STEP_RELOAD(gB2, 1, 0)
                STEP_RELOAD(gB3, 1, 0)
                STEP_RELOAD(gB4, 1, 0)
                STEP_RELOAD(gB5, 1, 0)
                STEP_RELOAD(gB6, 1, 0)
                STEP_RELOAD(gB7, 1, 1)
            }
            if (s + 0  < cnt) { STEP_NR(gA0, 1, 1) }
            if (s + 1  < cnt) { STEP_NR(gA1, 1, 1) }
            if (s + 2  < cnt) { STEP_NR(gA2, 1, 1) }
            if (s + 3  < cnt) { STEP_NR(gA3, 1, 1) }
            if (s + 4  < cnt) { STEP_NR(gA4, 1, 1) }
            if (s + 5  < cnt) { STEP_NR(gA5, 1, 1) }
            if (s + 6  < cnt) { STEP_NR(gA6, 1, 1) }
            if (s + 7  < cnt) { STEP_NR(gA7, 1, 1) }
            if (s + 8  < cnt) { STEP_NR(gB0, 1, 1) }
            if (s + 9  < cnt) { STEP_NR(gB1, 1, 1) }
            if (s + 10 < cnt) { STEP_NR(gB2, 1, 1) }
            if (s + 11 < cnt) { STEP_NR(gB3, 1, 1) }
            if (s + 12 < cnt) { STEP_NR(gB4, 1, 1) }
            if (s + 13 < cnt) { STEP_NR(gB5, 1, 1) }
            if (s + 14 < cnt) { STEP_NR(gB6, 1, 1) }
        }
        if (!up) {
            sRes[wave][j] = S;
            if (j == 0) sM2[wave] = M2i;
        }
    } else {
        // ================= gold waves (pure gathers) ========================
        int b = blockIdx.x * 4 + (wave - 8);
        if (b < B) {
            b = __builtin_amdgcn_readfirstlane(b);
            const int n = wsl[b];
            const float* __restrict__ frow = feats + (size_t)b * L * NTAG;
            const int*   __restrict__ trow = tags  + (size_t)b * L;
            float acc = 0.f;
            for (int tt = lane; tt < L; tt += 64) {
                const int tg = trow[tt];
                if (tt == 0) {
                    acc += strans[START * NTAG + tg] + frow[tg];
                } else if (tt < n) {
                    const int tgp = trow[tt - 1];
                    acc += strans[tgp * NTAG + tg] + frow[tt * NTAG + tg];
                }
                if (tt == n - 1) {
                    acc += strans[tg * NTAG + STOP];
                }
            }
#pragma unroll
            for (int k = 1; k < 64; k <<= 1) acc += __shfl_xor(acc, k, 64);
            if (lane == 0) atomicAdd(out, -acc);
        }
    }

    __syncthreads();

    // ============== combine: forward score = ln2*(M2f+M2b+log2(x . S)) ======
    if (wave < 4) {
        const int b2 = blockIdx.x * 4 + wave;
        if (b2 < B && lane < 32) {
            float ex = sRes[wave][lane] * sRes[wave + 4][lane];
#pragma unroll
            for (int k = 1; k < 32; k <<= 1) ex += __shfl_xor(ex, k, 32);
            if (lane == 0)
                atomicAdd(out, LN2 * ((float)(sM2[wave] + sM2[wave + 4]) + flog2(ex)));
        }
    }
}

extern "C" void kernel_launch(void* const* d_in, const int* in_sizes, int n_in,
                              void* d_out, int out_size, void* d_ws, size_t ws_size,
                              hipStream_t stream) {
    const float* feats = (const float*)d_in[0];
    const float* trans = (const float*)d_in[1];
    const int*   tags  = (const int*)d_in[2];
    const int*   wsl   = (const int*)d_in[3];
    float* out = (float*)d_out;

    const int B = in_sizes[3];              // word_seq_lens: (B,)
    const int L = in_sizes[2] / B;          // tags: (B, L)

    (void)hipMemsetAsync(out, 0, sizeof(float), stream);
    const int grid = (B + 3) / 4;
    crf_nll_kernel<<<grid, 768, 0, stream>>>(feats, trans, tags, wsl, out, B, L);
}